// Round 7
// baseline (1607.151 us; speedup 1.0000x reference)
//
#include <hip/hip_runtime.h>
#include <hip/hip_bf16.h>

// Problem constants
#define NBATCH 32
#define NTIME  2048
#define NOBJ   18
#define KIN    1500
#define NH     512
#define NTOT   1536   // 2H + DOUT
#define NM     65536  // NBATCH*NTIME

typedef __attribute__((ext_vector_type(4))) float f32x4;
typedef __attribute__((ext_vector_type(8))) short s16x8;
typedef __attribute__((ext_vector_type(4))) short s16x4;

static __device__ __forceinline__ short f2bf(float f) {
  union { float f; unsigned u; } v; v.f = f;
  unsigned r = v.u + 0x7fffu + ((v.u >> 16) & 1u);
  return (short)(r >> 16);
}

static __device__ __forceinline__ void gload_lds16(const short* g, short* l) {
  __builtin_amdgcn_global_load_lds(
      (const __attribute__((address_space(1))) unsigned int*)(g),
      (__attribute__((address_space(3))) unsigned int*)(l), 16, 0, 0);
}

#define FENCE() asm volatile("" ::: "memory")
#define BAR()   do { FENCE(); __builtin_amdgcn_s_barrier(); FENCE(); } while (0)
#define LGKM0() asm volatile("s_waitcnt lgkmcnt(0)" ::: "memory")

// Transpose+convert+pad src[K][Nsrc] f32 -> bf16 chunks [cb][kt][row256][kc64],
// with the LDS XOR swizzle baked into the global layout (kc ^ ((row&7)<<3)).
__global__ void k_prep(const float* __restrict__ src, short* __restrict__ dst,
                       int K, int Nsrc, int nkt, int total) {
  int i = blockIdx.x * 256 + threadIdx.x;
  if (i >= total) return;
  int chunk = i >> 14, off = i & 16383;
  int row = off >> 6, kcp = off & 63;
  int kc = kcp ^ ((row & 7) << 3);
  int cb = chunk / nkt, kt = chunk - cb * nkt;
  int n = cb * 256 + row, k = kt * 64 + kc;
  dst[i] = (k < K) ? f2bf(src[(size_t)k * Nsrc + n]) : (short)0;
}

__global__ void k_zero(float* __restrict__ p, int n) {
  int i = blockIdx.x * 256 + threadIdx.x;
  if (i < n) p[i] = 0.f;
}

// FUSED: per 64-row block:
//  phase 1: h = relu(trip @ w1a + b1a) -> LDS (64x512 bf16, swizzled).
//    A: reg-staged per 128-wide K-super (512 B contiguous per row read),
//    single-buffered lA [64][128]; B: wt1a chunks DMA'd, double-buffered.
//  phase 2: new_t = relu(h @ w1b + b1b) per 256-col panel (6 panels), h read
//    from LDS (no global A traffic), B: wt1b chunks DMA'd. Dead s/o panels
//    skipped exactly when the whole 64-row range is masked.
// hbuf and the separate gemm2 kernel are eliminated.
__launch_bounds__(512, 2)
__global__ void k_fused(const float* __restrict__ A, const short* __restrict__ B1c,
                        const float* __restrict__ b1a, const short* __restrict__ B2c,
                        const float* __restrict__ b1b, const int* __restrict__ index,
                        const int* __restrict__ rel_lens,
                        float* __restrict__ contrib, float* __restrict__ out) {
  __shared__ short hS[64 * 512];      // 64 KB
  __shared__ short lA[64 * 128];      // 16 KB (single-buffered A super)
  __shared__ short lB[2][256 * 64];   // 64 KB
  const int g = blockIdx.x;
  const int lid = (g & 7) * 128 + (g >> 3);   // 1024 blocks, bijective
  const int m0 = lid * 64;
  const int b = m0 >> 11;
  const int rel = rel_lens[b];
  const int tid = threadIdx.x;
  const int lane = tid & 63, w = tid >> 6;
  const int wr = w >> 2, wc = w & 3;          // 2x4 waves, wave tile 32x64
  const int rlane = lane & 15, ksel = (lane >> 4) * 8;
  const int arow = tid >> 3;                  // 0..63 (A-stage row)
  const int aseg = tid & 7;                   // 8 segs x 64 B per row

  f32x4 acc1[2][2][4] = {};   // [half][m][nn]
  float4 av[4];
  s16x8 af[2], bfr[4];

  auto issueA = [&](int u) {    // super u: k in [u*128, u*128+128)
#pragma unroll
    for (int i = 0; i < 4; ++i) {
      int k = u * 128 + aseg * 16 + i * 4;
      const float* p = A + (size_t)(m0 + arow) * KIN + k;
      av[i] = (k + 4 <= KIN) ? *(const float4*)p : make_float4(0.f, 0.f, 0.f, 0.f);
    }
  };
  auto writeA = [&]() {
#pragma unroll
    for (int i = 0; i < 4; ++i) {
      int c = aseg * 16 + i * 4;  // 0..124 within super
      s16x4 h4;
      h4[0] = f2bf(av[i].x); h4[1] = f2bf(av[i].y);
      h4[2] = f2bf(av[i].z); h4[3] = f2bf(av[i].w);
      *(s16x4*)&lA[arow * 128 + (c & 64) + ((c & 63) ^ ((arow & 7) << 3))] = h4;
    }
  };
  auto issueB1 = [&](int nb, int cb, int kt) {
    const short* src = B1c + (size_t)(cb * 24 + kt) * 16384 + tid * 8;
#pragma unroll
    for (int i = 0; i < 4; ++i)
      gload_lds16(src + i * 4096, &lB[nb][tid * 8 + i * 4096]);
  };
  auto issueB2 = [&](int nb, int p, int kt) {
    const short* src = B2c + (size_t)(p * 8 + kt) * 16384 + tid * 8;
#pragma unroll
    for (int i = 0; i < 4; ++i)
      gload_lds16(src + i * 4096, &lB[nb][tid * 8 + i * 4096]);
  };

  // ---- phase 1: 48 steps; step s -> u = s>>2, half = (s>>1)&1, sub = s&1.
  // B1 chunk for step = (cb=half, kt=u*2+sub). A super staged every 4 steps.
  issueA(0);
  issueB1(0, 0, 0);
  asm volatile("s_waitcnt vmcnt(0)" ::: "memory");
  writeA();
  LGKM0();
  BAR();

#pragma unroll 1
  for (int s = 0; s < 48; ++s) {
    const int u = s >> 2, half = (s >> 1) & 1, sub = s & 1;
    const int cu = s & 1;
    if (s < 47) {
      const int s1 = s + 1;
      issueB1(cu ^ 1, (s1 >> 1) & 1, (s1 >> 2) * 2 + (s1 & 1));
    }
    const bool aIss = ((s & 3) == 1) && (u < 11);
    if (aIss) issueA(u + 1);   // after B-issue: queue [B4, A4]
    // compute(half, sub)
#pragma unroll
    for (int j = 0; j < 2; ++j) {
      int k0 = j * 32 + ksel;
#pragma unroll
      for (int m = 0; m < 2; ++m) {
        int row = wr * 32 + m * 16 + rlane;
        af[m] = *(const s16x8*)&lA[row * 128 + sub * 64 + (k0 ^ ((row & 7) << 3))];
      }
#pragma unroll
      for (int nn = 0; nn < 4; ++nn) {
        int row = wc * 64 + nn * 16 + rlane;
        bfr[nn] = *(const s16x8*)&lB[cu][row * 64 + (k0 ^ ((row & 7) << 3))];
      }
#pragma unroll
      for (int m = 0; m < 2; ++m)
#pragma unroll
        for (int nn = 0; nn < 4; ++nn)
          acc1[half][m][nn] = __builtin_amdgcn_mfma_f32_16x16x32_bf16(
              af[m], bfr[nn], acc1[half][m][nn], 0, 0, 0);
    }
    if (s < 47) {
      if (aIss) { asm volatile("s_waitcnt vmcnt(4)" ::: "memory"); }  // keep A in flight
      else      { asm volatile("s_waitcnt vmcnt(0)" ::: "memory"); }
      BAR();
      if (((s & 3) == 3) && (u < 11)) {   // super boundary: stage A(u+1)
        writeA();
        LGKM0();
        BAR();
      }
    }
  }

  // h-epilogue: relu(acc1 + b1a) -> hS (swizzled), then barrier
#pragma unroll
  for (int half = 0; half < 2; ++half)
#pragma unroll
    for (int nn = 0; nn < 4; ++nn) {
      int c = half * 256 + wc * 64 + nn * 16 + rlane;
      float bv = b1a[c];
      int csw = (c & ~63);
#pragma unroll
      for (int m = 0; m < 2; ++m) {
        int lr0 = wr * 32 + m * 16 + ((lane >> 4) << 2);
#pragma unroll
        for (int q = 0; q < 4; ++q) {
          int lr = lr0 + q;
          float v = acc1[half][m][nn][q] + bv;
          v = v > 0.f ? v : 0.f;
          hS[lr * 512 + csw + ((c & 63) ^ ((lr & 7) << 3))] = f2bf(v);
        }
      }
    }
  LGKM0();
  BAR();

  // ---- phase 2: 6 panels of 256 cols; K=512 from hS; B2 chunks DMA'd.
#pragma unroll 1
  for (int p = 0; p < 6; ++p) {
    const int region = p >> 1;  // 0:s 1:p 2:o
    if (region != 1 && (m0 & 2047) >= rel) continue;  // dead s/o panel

    f32x4 acc2[2][4] = {};
    issueB2(0, p, 0);
    asm volatile("s_waitcnt vmcnt(0)" ::: "memory");
    BAR();
#pragma unroll 1
    for (int kt = 0; kt < 8; ++kt) {
      const int cu = kt & 1;
      if (kt < 7) issueB2(cu ^ 1, p, kt + 1);
#pragma unroll
      for (int j = 0; j < 2; ++j) {
        int k0 = j * 32 + ksel;
#pragma unroll
        for (int m = 0; m < 2; ++m) {
          int row = wr * 32 + m * 16 + rlane;
          af[m] = *(const s16x8*)&hS[row * 512 + kt * 64 + (k0 ^ ((row & 7) << 3))];
        }
#pragma unroll
        for (int nn = 0; nn < 4; ++nn) {
          int row = wc * 64 + nn * 16 + rlane;
          bfr[nn] = *(const s16x8*)&lB[cu][row * 64 + (k0 ^ ((row & 7) << 3))];
        }
#pragma unroll
        for (int m = 0; m < 2; ++m)
#pragma unroll
          for (int nn = 0; nn < 4; ++nn)
            acc2[m][nn] = __builtin_amdgcn_mfma_f32_16x16x32_bf16(
                af[m], bfr[nn], acc2[m][nn], 0, 0, 0);
      }
      if (kt < 7) {
        asm volatile("s_waitcnt vmcnt(0)" ::: "memory");
        BAR();
      }
    }

    // panel epilogue
    float bv[4]; int cg[4];
#pragma unroll
    for (int nn = 0; nn < 4; ++nn) {
      cg[nn] = p * 256 + wc * 64 + nn * 16 + rlane;
      bv[nn] = b1b[cg[nn]];
    }
    if (region == 1) {
      float* po = out + (size_t)NBATCH * NOBJ * NH;  // p_vecs region of d_out
#pragma unroll
      for (int m = 0; m < 2; ++m) {
        int rbase = m0 + wr * 32 + m * 16 + ((lane >> 4) << 2);
#pragma unroll
        for (int q = 0; q < 4; ++q) {
#pragma unroll
          for (int nn = 0; nn < 4; ++nn) {
            float v = acc2[m][nn][q] + bv[nn];
            v = v > 0.f ? v : 0.f;
            po[(size_t)(rbase + q) * NH + (cg[nn] & 511)] = v;
          }
        }
      }
    } else {
      const int sel = region >> 1;   // 0 for s, 1 for o
#pragma unroll
      for (int m = 0; m < 2; ++m) {
        int rbase = m0 + wr * 32 + m * 16 + ((lane >> 4) << 2);
#pragma unroll
        for (int q = 0; q < 4; ++q) {
          int r = rbase + q;
          if ((r & 2047) < rel) {
            int idx = index[2 * r + sel];
            float* dst = contrib + ((b * NOBJ + idx) << 9);
#pragma unroll
            for (int nn = 0; nn < 4; ++nn) {
              float v = acc2[m][nn][q] + bv[nn];
              v = v > 0.f ? v : 0.f;
              atomicAdd(dst + (cg[nn] & 511), v);
            }
          }
        }
      }
    }
  }
}

// pooled[b] = cumsum_b(contrib)
__global__ void k_cumsum(const float* __restrict__ contrib, float* __restrict__ pooled) {
  int i = blockIdx.x * 256 + threadIdx.x;
  if (i >= NOBJ * NH) return;
  float a = 0.f;
#pragma unroll
  for (int b = 0; b < NBATCH; ++b) {
    a += contrib[b * (NOBJ * NH) + i];
    pooled[b * (NOBJ * NH) + i] = a;
  }
}

// new_obj = relu(relu(pooled @ w2a + b2a) @ w2b + b2b), one block per (b,o)
// row. 4 independent FMA chains per thread.
__global__ void k_mlp2(const float* __restrict__ pooled,
                       const float* __restrict__ w2a, const float* __restrict__ b2a,
                       const float* __restrict__ w2b, const float* __restrict__ b2b,
                       float* __restrict__ out) {
  __shared__ float pr[NH];
  __shared__ float hr[NH];
  int row = blockIdx.x;
  int tid = threadIdx.x;
  pr[tid]       = pooled[(size_t)row * NH + tid];
  pr[tid + 256] = pooled[(size_t)row * NH + tid + 256];
  __syncthreads();
  {
    float a0 = 0.f, a1 = 0.f, b0 = 0.f, b1 = 0.f;
    for (int k = 0; k < NH; k += 2) {
      float p0 = pr[k], p1 = pr[k + 1];
      a0 += p0 * w2a[(size_t)k * NH + tid];
      b0 += p0 * w2a[(size_t)k * NH + tid + 256];
      a1 += p1 * w2a[(size_t)(k + 1) * NH + tid];
      b1 += p1 * w2a[(size_t)(k + 1) * NH + tid + 256];
    }
    float s0 = a0 + a1 + b2a[tid], s1 = b0 + b1 + b2a[tid + 256];
    hr[tid]       = s0 > 0.f ? s0 : 0.f;
    hr[tid + 256] = s1 > 0.f ? s1 : 0.f;
  }
  __syncthreads();
  {
    float a0 = 0.f, a1 = 0.f, b0 = 0.f, b1 = 0.f;
    for (int k = 0; k < NH; k += 2) {
      float h0 = hr[k], h1 = hr[k + 1];
      a0 += h0 * w2b[(size_t)k * NH + tid];
      b0 += h0 * w2b[(size_t)k * NH + tid + 256];
      a1 += h1 * w2b[(size_t)(k + 1) * NH + tid];
      b1 += h1 * w2b[(size_t)(k + 1) * NH + tid + 256];
    }
    float s0 = a0 + a1 + b2b[tid], s1 = b0 + b1 + b2b[tid + 256];
    out[(size_t)row * NH + tid]       = s0 > 0.f ? s0 : 0.f;
    out[(size_t)row * NH + tid + 256] = s1 > 0.f ? s1 : 0.f;
  }
}

extern "C" void kernel_launch(void* const* d_in, const int* in_sizes, int n_in,
                              void* d_out, int out_size, void* d_ws, size_t ws_size,
                              hipStream_t stream) {
  const float* trip     = (const float*)d_in[0];
  const int*   index    = (const int*)d_in[1];
  const int*   rel_lens = (const int*)d_in[2];
  const float* w1a      = (const float*)d_in[3];
  const float* b1a      = (const float*)d_in[4];
  const float* w1b      = (const float*)d_in[5];
  const float* b1b      = (const float*)d_in[6];
  const float* w2a      = (const float*)d_in[7];
  const float* b2a      = (const float*)d_in[8];
  const float* w2b      = (const float*)d_in[9];
  const float* b2b      = (const float*)d_in[10];
  float* out = (float*)d_out;

  char* ws = (char*)d_ws;
  short* wt1a    = (short*)(ws);                          // 512*1536 bf16  (1.50 MB)
  short* wt1b    = (short*)(ws + 1572864);                // 1536*512 bf16  (1.50 MB)
  float* contrib = (float*)(ws + 3145728);                // 32*18*512 f32
  float* pooled  = contrib + NBATCH * NOBJ * NH;

  k_zero<<<1152, 256, 0, stream>>>(contrib, NBATCH * NOBJ * NH);
  k_prep<<<3072, 256, 0, stream>>>(w1a, wt1a, KIN, NH, 24, NH * 1536);
  k_prep<<<3072, 256, 0, stream>>>(w1b, wt1b, NH, NTOT, 8, NTOT * NH);
  k_fused<<<1024, 512, 0, stream>>>(trip, wt1a, b1a, wt1b, b1b, index, rel_lens,
                                    contrib, out);
  k_cumsum<<<36, 256, 0, stream>>>(contrib, pooled);
  k_mlp2<<<576, 256, 0, stream>>>(pooled, w2a, b2a, w2b, b2b, out);
}

// Round 8
// 549.602 us; speedup vs baseline: 2.9242x; 2.9242x over previous
//
#include <hip/hip_runtime.h>
#include <hip/hip_bf16.h>

// Problem constants
#define NBATCH 32
#define NTIME  2048
#define NOBJ   18
#define KIN    1500
#define NH     512
#define NTOT   1536   // 2H + DOUT
#define NM     65536  // NBATCH*NTIME

typedef __attribute__((ext_vector_type(4))) float f32x4;
typedef __attribute__((ext_vector_type(8))) short s16x8;
typedef __attribute__((ext_vector_type(4))) short s16x4;

static __device__ __forceinline__ short f2bf(float f) {
  union { float f; unsigned u; } v; v.f = f;
  unsigned r = v.u + 0x7fffu + ((v.u >> 16) & 1u);
  return (short)(r >> 16);
}

static __device__ __forceinline__ void gload_lds16(const short* g, short* l) {
  __builtin_amdgcn_global_load_lds(
      (const __attribute__((address_space(1))) unsigned int*)(g),
      (__attribute__((address_space(3))) unsigned int*)(l), 16, 0, 0);
}

#define FENCE() asm volatile("" ::: "memory")
#define BAR()   do { FENCE(); __builtin_amdgcn_s_barrier(); FENCE(); } while (0)
#define LGKM0() asm volatile("s_waitcnt lgkmcnt(0)" ::: "memory")

// Transpose+convert+pad src[K][Nsrc] f32 -> bf16 chunks [cb][kt][row256][kc64],
// with the LDS XOR swizzle baked into the global layout (kc ^ ((row&7)<<3)).
__global__ void k_prep(const float* __restrict__ src, short* __restrict__ dst,
                       int K, int Nsrc, int nkt, int total) {
  int i = blockIdx.x * 256 + threadIdx.x;
  if (i >= total) return;
  int chunk = i >> 14, off = i & 16383;
  int row = off >> 6, kcp = off & 63;
  int kc = kcp ^ ((row & 7) << 3);
  int cb = chunk / nkt, kt = chunk - cb * nkt;
  int n = cb * 256 + row, k = kt * 64 + kc;
  dst[i] = (k < K) ? f2bf(src[(size_t)k * Nsrc + n]) : (short)0;
}

__global__ void k_zero(float* __restrict__ p, int n) {
  int i = blockIdx.x * 256 + threadIdx.x;
  if (i < n) p[i] = 0.f;
}

// GEMM1: h = relu(trip @ w1a + b1a). FULL-N tile: 128 rows x 512 cols, BK=64.
// A read from HBM exactly once (393 MB total demand, was 786); B demand
// halved (512 blocks x 1.5 MB). Per-step in-flight = 64 KB B-DMA + 8 KB A
// per CU -> latency covered by volume, not schedule. lA single-buffered
// (written between the two per-step barriers), lB double-buffered.
// 8 waves (2x4), wave tile 64x128, acc[4][8] (128 VGPR).
__launch_bounds__(512, 2)
__global__ void k_gemm1(const float* __restrict__ A, const short* __restrict__ Bc,
                        const float* __restrict__ bias, short* __restrict__ Hc) {
  __shared__ short lA[128 * 64];      // 16 KB, single-buffered
  __shared__ short lB[2][512 * 64];   // 128 KB
  const int g = blockIdx.x;
  const int lid = (g & 7) * 64 + (g >> 3);   // 512 blocks, bijective XCD swizzle
  const int m0 = lid * 128;
  const int tid = threadIdx.x;
  const int lane = tid & 63, w = tid >> 6;
  const int wr = w >> 2, wc = w & 3;          // wave tile 64x128
  const int rlane = lane & 15, ksel = (lane >> 4) * 8;
  const int arow = tid >> 2;                  // 0..127 (one row per thread)
  const int akq  = (tid & 3) * 16;            // 4 thr/row x 16 floats (64 B)

  f32x4 acc[4][8] = {};
  float4 av[4];
  s16x8 af[4], bfr[8];

  auto issueAregs = [&](int kt) {
    const int kbase = kt * 64 + akq;
#pragma unroll
    for (int i = 0; i < 4; ++i) {
      int k = kbase + i * 4;
      const float* p = A + (size_t)(m0 + arow) * KIN + k;
      av[i] = (k + 4 <= KIN) ? *(const float4*)p : make_float4(0.f, 0.f, 0.f, 0.f);
    }
  };
  auto writeA = [&]() {
#pragma unroll
    for (int i = 0; i < 4; ++i) {
      int c = akq + i * 4;
      s16x4 h4;
      h4[0] = f2bf(av[i].x); h4[1] = f2bf(av[i].y);
      h4[2] = f2bf(av[i].z); h4[3] = f2bf(av[i].w);
      *(s16x4*)&lA[arow * 64 + (c ^ ((arow & 7) << 3))] = h4;
    }
  };
  auto issueB = [&](int nb, int kt) {   // both cb halves: 512x64 = 64 KB
#pragma unroll
    for (int h = 0; h < 2; ++h) {
      const short* src = Bc + (size_t)(h * 24 + kt) * 16384 + tid * 8;
#pragma unroll
      for (int i = 0; i < 4; ++i)
        gload_lds16(src + i * 4096, &lB[nb][h * 16384 + tid * 8 + i * 4096]);
    }
  };
  auto compute = [&](int cu) {
#pragma unroll
    for (int j = 0; j < 2; ++j) {
      int k0 = j * 32 + ksel;
#pragma unroll
      for (int m = 0; m < 4; ++m) {
        int row = wr * 64 + m * 16 + rlane;
        af[m] = *(const s16x8*)&lA[row * 64 + (k0 ^ ((row & 7) << 3))];
      }
#pragma unroll
      for (int nn = 0; nn < 8; ++nn) {
        int row = wc * 128 + nn * 16 + rlane;
        bfr[nn] = *(const s16x8*)&lB[cu][row * 64 + (k0 ^ ((row & 7) << 3))];
      }
#pragma unroll
      for (int m = 0; m < 4; ++m)
#pragma unroll
        for (int nn = 0; nn < 8; ++nn)
          acc[m][nn] = __builtin_amdgcn_mfma_f32_16x16x32_bf16(af[m], bfr[nn], acc[m][nn], 0, 0, 0);
    }
  };

  // Prologue: A regs + B(0); write lA; drain; barrier.
  issueAregs(0);
  issueB(0, 0);
  writeA();                                       // compiler waits av loads
  LGKM0();
  asm volatile("s_waitcnt vmcnt(0)" ::: "memory");
  BAR();

#pragma unroll 1
  for (int kt = 0; kt < 24; ++kt) {
    const int cu = kt & 1;
    if (kt < 23) { issueAregs(kt + 1); issueB(cu ^ 1, kt + 1); }
    compute(cu);
    BAR();                                        // all waves done reading lA
    if (kt < 23) {
      writeA();                                   // stage A(kt+1) into lA
      LGKM0();
      asm volatile("s_waitcnt vmcnt(0)" ::: "memory");  // B(kt+1) landed
      BAR();
    }
  }

  // epilogue: bias + relu, store to chunked-swizzled layout for GEMM2's A
#pragma unroll
  for (int nn = 0; nn < 8; ++nn) {
    int c = wc * 128 + nn * 16 + rlane;
    float bv = bias[c];
#pragma unroll
    for (int m = 0; m < 4; ++m) {
      int rbase = m0 + wr * 64 + m * 16 + ((lane >> 4) << 2);
#pragma unroll
      for (int q = 0; q < 4; ++q) {
        int r = rbase + q;
        float v = acc[m][nn][q] + bv;
        v = v > 0.f ? v : 0.f;
        Hc[(size_t)(((r >> 7) * 8 + (c >> 6)) * 8192) + (r & 127) * 64 +
           ((c & 63) ^ ((r & 7) << 3))] = f2bf(v);
      }
    }
  }
}

// GEMM2: new_t = relu(h @ w1b + b1b). One block per 64-row strip: block's A
// (64x512 bf16 = 64 KB) staged into LDS ONCE (chunk-major [ct][64][64],
// row stride 128 B = bank-free, DMA-linear), then all 6 N-panels computed
// from it (A demand /6). Dead s/o panels skipped exactly. lB double-buffered
// per panel (round-6 proven loop). Scatter epilogue unchanged.
__launch_bounds__(512, 2)
__global__ void k_gemm2(const short* __restrict__ Ac, const short* __restrict__ Bc,
                        const float* __restrict__ bias, const int* __restrict__ index,
                        const int* __restrict__ rel_lens,
                        float* __restrict__ contrib, float* __restrict__ out) {
  __shared__ short hA[8 * 64 * 64];   // 64 KB (persistent A)
  __shared__ short lB[2][256 * 64];   // 64 KB
  const int g = blockIdx.x;
  const int lid = (g & 7) * 128 + (g >> 3);   // 1024 blocks, bijective
  const int m0 = lid * 64;
  const int b = m0 >> 11;
  const int rel = rel_lens[b];
  const int tid = threadIdx.x;
  const int lane = tid & 63, w = tid >> 6;
  const int wr = w >> 2, wc = w & 3;
  const int rlane = lane & 15, ksel = (lane >> 4) * 8;

  // Stage A once: chunk ct holds cols [ct*64, ct*64+64) of rows m0..m0+63.
  {
    const short* srcbase = Ac + (size_t)((m0 >> 7) * 8) * 8192 + (m0 & 127) * 64;
#pragma unroll
    for (int ct = 0; ct < 8; ++ct)
      gload_lds16(srcbase + (size_t)ct * 8192 + tid * 8, &hA[ct * 4096 + tid * 8]);
  }
  // First panel's first B chunk piggybacks on the same drain below.

  s16x8 af[2], bfr[4];
  auto issueB2 = [&](int nb, int p, int kt) {
    const short* src = Bc + (size_t)(p * 8 + kt) * 16384 + tid * 8;
#pragma unroll
    for (int i = 0; i < 4; ++i)
      gload_lds16(src + i * 4096, &lB[nb][tid * 8 + i * 4096]);
  };

  bool first = true;
#pragma unroll 1
  for (int p = 0; p < 6; ++p) {
    const int region = p >> 1;  // 0:s 1:p 2:o
    if (region != 1 && (m0 & 2047) >= rel) continue;  // dead s/o panel

    f32x4 acc[2][4] = {};
    issueB2(0, p, 0);
    asm volatile("s_waitcnt vmcnt(0)" ::: "memory");  // drains hA stage too (first)
    BAR();
    (void)first; first = false;

#pragma unroll 1
    for (int kt = 0; kt < 8; ++kt) {
      const int cu = kt & 1;
      if (kt < 7) issueB2(cu ^ 1, p, kt + 1);
#pragma unroll
      for (int j = 0; j < 2; ++j) {
        int k0 = j * 32 + ksel;
#pragma unroll
        for (int m = 0; m < 2; ++m) {
          int row = wr * 32 + m * 16 + rlane;
          af[m] = *(const s16x8*)&hA[kt * 4096 + row * 64 + (k0 ^ ((row & 7) << 3))];
        }
#pragma unroll
        for (int nn = 0; nn < 4; ++nn) {
          int row = wc * 64 + nn * 16 + rlane;
          bfr[nn] = *(const s16x8*)&lB[cu][row * 64 + (k0 ^ ((row & 7) << 3))];
        }
#pragma unroll
        for (int m = 0; m < 2; ++m)
#pragma unroll
          for (int nn = 0; nn < 4; ++nn)
            acc[m][nn] = __builtin_amdgcn_mfma_f32_16x16x32_bf16(af[m], bfr[nn], acc[m][nn], 0, 0, 0);
      }
      if (kt < 7) {
        asm volatile("s_waitcnt vmcnt(0)" ::: "memory");
        BAR();
      }
    }

    float bv[4]; int cg[4];
#pragma unroll
    for (int nn = 0; nn < 4; ++nn) {
      cg[nn] = p * 256 + wc * 64 + nn * 16 + rlane;
      bv[nn] = bias[cg[nn]];
    }
    if (region == 1) {
      float* po = out + (size_t)NBATCH * NOBJ * NH;  // p_vecs region of d_out
#pragma unroll
      for (int m = 0; m < 2; ++m) {
        int rbase = m0 + wr * 32 + m * 16 + ((lane >> 4) << 2);
#pragma unroll
        for (int q = 0; q < 4; ++q) {
#pragma unroll
          for (int nn = 0; nn < 4; ++nn) {
            float v = acc[m][nn][q] + bv[nn];
            v = v > 0.f ? v : 0.f;
            po[(size_t)(rbase + q) * NH + (cg[nn] & 511)] = v;
          }
        }
      }
    } else {
      const int sel = region >> 1;   // 0 for s, 1 for o
#pragma unroll
      for (int m = 0; m < 2; ++m) {
        int rbase = m0 + wr * 32 + m * 16 + ((lane >> 4) << 2);
#pragma unroll
        for (int q = 0; q < 4; ++q) {
          int r = rbase + q;
          if ((r & 2047) < rel) {
            int idx = index[2 * r + sel];
            float* dst = contrib + ((b * NOBJ + idx) << 9);
#pragma unroll
            for (int nn = 0; nn < 4; ++nn) {
              float v = acc[m][nn][q] + bv[nn];
              v = v > 0.f ? v : 0.f;
              atomicAdd(dst + (cg[nn] & 511), v);
            }
          }
        }
      }
    }
    // lB buffer safety across panels: last kt reads lB[1]; next panel's
    // prologue writes lB[0] -> disjoint; prologue drain+BAR orders the rest.
  }
}

// pooled[b] = cumsum_b(contrib)
__global__ void k_cumsum(const float* __restrict__ contrib, float* __restrict__ pooled) {
  int i = blockIdx.x * 256 + threadIdx.x;
  if (i >= NOBJ * NH) return;
  float a = 0.f;
#pragma unroll
  for (int b = 0; b < NBATCH; ++b) {
    a += contrib[b * (NOBJ * NH) + i];
    pooled[b * (NOBJ * NH) + i] = a;
  }
}

// new_obj = relu(relu(pooled @ w2a + b2a) @ w2b + b2b), one block per (b,o)
// row. 4 independent FMA chains per thread.
__global__ void k_mlp2(const float* __restrict__ pooled,
                       const float* __restrict__ w2a, const float* __restrict__ b2a,
                       const float* __restrict__ w2b, const float* __restrict__ b2b,
                       float* __restrict__ out) {
  __shared__ float pr[NH];
  __shared__ float hr[NH];
  int row = blockIdx.x;
  int tid = threadIdx.x;
  pr[tid]       = pooled[(size_t)row * NH + tid];
  pr[tid + 256] = pooled[(size_t)row * NH + tid + 256];
  __syncthreads();
  {
    float a0 = 0.f, a1 = 0.f, b0 = 0.f, b1 = 0.f;
    for (int k = 0; k < NH; k += 2) {
      float p0 = pr[k], p1 = pr[k + 1];
      a0 += p0 * w2a[(size_t)k * NH + tid];
      b0 += p0 * w2a[(size_t)k * NH + tid + 256];
      a1 += p1 * w2a[(size_t)(k + 1) * NH + tid];
      b1 += p1 * w2a[(size_t)(k + 1) * NH + tid + 256];
    }
    float s0 = a0 + a1 + b2a[tid], s1 = b0 + b1 + b2a[tid + 256];
    hr[tid]       = s0 > 0.f ? s0 : 0.f;
    hr[tid + 256] = s1 > 0.f ? s1 : 0.f;
  }
  __syncthreads();
  {
    float a0 = 0.f, a1 = 0.f, b0 = 0.f, b1 = 0.f;
    for (int k = 0; k < NH; k += 2) {
      float h0 = hr[k], h1 = hr[k + 1];
      a0 += h0 * w2b[(size_t)k * NH + tid];
      b0 += h0 * w2b[(size_t)k * NH + tid + 256];
      a1 += h1 * w2b[(size_t)(k + 1) * NH + tid];
      b1 += h1 * w2b[(size_t)(k + 1) * NH + tid + 256];
    }
    float s0 = a0 + a1 + b2b[tid], s1 = b0 + b1 + b2b[tid + 256];
    out[(size_t)row * NH + tid]       = s0 > 0.f ? s0 : 0.f;
    out[(size_t)row * NH + tid + 256] = s1 > 0.f ? s1 : 0.f;
  }
}

extern "C" void kernel_launch(void* const* d_in, const int* in_sizes, int n_in,
                              void* d_out, int out_size, void* d_ws, size_t ws_size,
                              hipStream_t stream) {
  const float* trip     = (const float*)d_in[0];
  const int*   index    = (const int*)d_in[1];
  const int*   rel_lens = (const int*)d_in[2];
  const float* w1a      = (const float*)d_in[3];
  const float* b1a      = (const float*)d_in[4];
  const float* w1b      = (const float*)d_in[5];
  const float* b1b      = (const float*)d_in[6];
  const float* w2a      = (const float*)d_in[7];
  const float* b2a      = (const float*)d_in[8];
  const float* w2b      = (const float*)d_in[9];
  const float* b2b      = (const float*)d_in[10];
  float* out = (float*)d_out;

  char* ws = (char*)d_ws;
  short* wt1a    = (short*)(ws);                          // 512*1536 bf16  (1.50 MB)
  short* wt1b    = (short*)(ws + 1572864);                // 1536*512 bf16  (1.50 MB)
  short* hbuf    = (short*)(ws + 3145728);                // 65536*512 bf16 (64 MB), chunked
  float* contrib = (float*)(ws + 70254592);               // 32*18*512 f32
  float* pooled  = contrib + NBATCH * NOBJ * NH;

  k_zero<<<1152, 256, 0, stream>>>(contrib, NBATCH * NOBJ * NH);
  k_prep<<<3072, 256, 0, stream>>>(w1a, wt1a, KIN, NH, 24, NH * 1536);
  k_prep<<<3072, 256, 0, stream>>>(w1b, wt1b, NH, NTOT, 8, NTOT * NH);
  k_gemm1<<<512, 512, 0, stream>>>(trip, wt1a, b1a, hbuf);
  k_gemm2<<<1024, 512, 0, stream>>>(hbuf, wt1b, b1b, index, rel_lens, contrib, out);
  k_cumsum<<<36, 256, 0, stream>>>(contrib, pooled);
  k_mlp2<<<576, 256, 0, stream>>>(pooled, w2a, b2a, w2b, b2b, out);
}

// Round 9
// 501.483 us; speedup vs baseline: 3.2048x; 1.0960x over previous
//
#include <hip/hip_runtime.h>
#include <hip/hip_bf16.h>

// Problem constants
#define NBATCH 32
#define NTIME  2048
#define NOBJ   18
#define KIN    1500
#define NH     512
#define NTOT   1536   // 2H + DOUT
#define NM     65536  // NBATCH*NTIME

typedef __attribute__((ext_vector_type(4))) float f32x4;
typedef __attribute__((ext_vector_type(8))) short s16x8;
typedef __attribute__((ext_vector_type(4))) short s16x4;

static __device__ __forceinline__ short f2bf(float f) {
  union { float f; unsigned u; } v; v.f = f;
  unsigned r = v.u + 0x7fffu + ((v.u >> 16) & 1u);
  return (short)(r >> 16);
}

static __device__ __forceinline__ void gload_lds16(const short* g, short* l) {
  __builtin_amdgcn_global_load_lds(
      (const __attribute__((address_space(1))) unsigned int*)(g),
      (__attribute__((address_space(3))) unsigned int*)(l), 16, 0, 0);
}

#define FENCE() asm volatile("" ::: "memory")
#define BAR()   do { FENCE(); __builtin_amdgcn_s_barrier(); FENCE(); } while (0)
#define LGKM0() asm volatile("s_waitcnt lgkmcnt(0)" ::: "memory")

// Transpose+convert+pad src[K][Nsrc] f32 -> bf16 chunks [cb][kt][row256][kc64],
// with the LDS XOR swizzle baked into the global layout (kc ^ ((row&7)<<3)).
__global__ void k_prep(const float* __restrict__ src, short* __restrict__ dst,
                       int K, int Nsrc, int nkt, int total) {
  int i = blockIdx.x * 256 + threadIdx.x;
  if (i >= total) return;
  int chunk = i >> 14, off = i & 16383;
  int row = off >> 6, kcp = off & 63;
  int kc = kcp ^ ((row & 7) << 3);
  int cb = chunk / nkt, kt = chunk - cb * nkt;
  int n = cb * 256 + row, k = kt * 64 + kc;
  dst[i] = (k < K) ? f2bf(src[(size_t)k * Nsrc + n]) : (short)0;
}

__global__ void k_zero(float* __restrict__ p, int n) {
  int i = blockIdx.x * 256 + threadIdx.x;
  if (i < n) p[i] = 0.f;
}

// GEMM1: h = relu(trip @ w1a + b1a). 128x256 tile, BK=64.
// Controlled completion of round-8's test: bigger M-tile (B L2-demand and
// LDS-reads/FLOP both halved vs 64-row) WITH 2 blocks/CU preserved:
// lA single-buffered 16 KB + lB dbuf 64 KB = 80 KB LDS exactly.
// 8 waves (2x4), wave tile 64x64, acc[4][4] (64 regs), ~124 VGPR total.
// A f32 reg-staged issue-early/write-late; B via global_load_lds.
__launch_bounds__(512, 2)
__global__ void k_gemm1(const float* __restrict__ A, const short* __restrict__ Bc,
                        const float* __restrict__ bias, short* __restrict__ Hc) {
  __shared__ short lA[128 * 64];      // 16 KB, single-buffered
  __shared__ short lB[2][256 * 64];   // 64 KB
  const int g = blockIdx.x;
  const int lid = (g & 7) * 128 + (g >> 3);   // 1024 blocks, bijective XCD swizzle
  const int rb = lid >> 1, cb = lid & 1;      // cb pair lands on same XCD
  const int m0 = rb * 128, n0 = cb * 256;
  const int tid = threadIdx.x;
  const int lane = tid & 63, w = tid >> 6;
  const int wr = w >> 2, wc = w & 3;          // 2x4 waves, wave tile 64x64
  const int rlane = lane & 15, ksel = (lane >> 4) * 8;
  const int arow = tid >> 2;                  // 0..127 (one row per thread)
  const int akq  = (tid & 3) * 16;            // 4 thr/row x 16 floats (64 B)
  const short* bchunk = Bc + (size_t)(cb * 24) * 16384;

  f32x4 acc[4][4] = {};
  float4 av[4];
  s16x8 af[4], bfr[4];

  auto issueAregs = [&](int kt) {
    const int kbase = kt * 64 + akq;
#pragma unroll
    for (int i = 0; i < 4; ++i) {
      int k = kbase + i * 4;
      const float* p = A + (size_t)(m0 + arow) * KIN + k;
      av[i] = (k + 4 <= KIN) ? *(const float4*)p : make_float4(0.f, 0.f, 0.f, 0.f);
    }
  };
  auto writeA = [&]() {
#pragma unroll
    for (int i = 0; i < 4; ++i) {
      int c = akq + i * 4;
      s16x4 h4;
      h4[0] = f2bf(av[i].x); h4[1] = f2bf(av[i].y);
      h4[2] = f2bf(av[i].z); h4[3] = f2bf(av[i].w);
      *(s16x4*)&lA[arow * 64 + (c ^ ((arow & 7) << 3))] = h4;
    }
  };
  auto issueB = [&](int nb, int kt) {   // 256x64 = 32 KB per step
    const short* src = bchunk + (size_t)kt * 16384 + tid * 8;
#pragma unroll
    for (int i = 0; i < 4; ++i)
      gload_lds16(src + i * 4096, &lB[nb][tid * 8 + i * 4096]);
  };
  auto compute = [&](int cu) {
#pragma unroll
    for (int j = 0; j < 2; ++j) {
      int k0 = j * 32 + ksel;
#pragma unroll
      for (int m = 0; m < 4; ++m) {
        int row = wr * 64 + m * 16 + rlane;
        af[m] = *(const s16x8*)&lA[row * 64 + (k0 ^ ((row & 7) << 3))];
      }
#pragma unroll
      for (int nn = 0; nn < 4; ++nn) {
        int row = wc * 64 + nn * 16 + rlane;
        bfr[nn] = *(const s16x8*)&lB[cu][row * 64 + (k0 ^ ((row & 7) << 3))];
      }
#pragma unroll
      for (int m = 0; m < 4; ++m)
#pragma unroll
        for (int nn = 0; nn < 4; ++nn)
          acc[m][nn] = __builtin_amdgcn_mfma_f32_16x16x32_bf16(af[m], bfr[nn], acc[m][nn], 0, 0, 0);
    }
  };

  // Prologue: A regs + B(0); write lA (compiler waits the A loads, leaving
  // the 4 B DMAs outstanding); drain B; barrier.
  issueAregs(0);
  issueB(0, 0);
  writeA();
  LGKM0();
  asm volatile("s_waitcnt vmcnt(0)" ::: "memory");
  BAR();

#pragma unroll 1
  for (int kt = 0; kt < 24; ++kt) {
    const int cu = kt & 1;
    if (kt < 23) { issueAregs(kt + 1); issueB(cu ^ 1, kt + 1); }
    compute(cu);
    BAR();                       // all waves done reading lA(kt)
    if (kt < 23) {
      writeA();                  // stage A(kt+1); compiler drains A loads only
      LGKM0();
      asm volatile("s_waitcnt vmcnt(0)" ::: "memory");  // B(kt+1) landed
      BAR();
    }
  }

  // epilogue: bias + relu, store to chunked-swizzled layout for GEMM2's A
  // (chunk id (r>>7)*8 + (c>>6), chunk 8192 shorts, proven reader pair)
#pragma unroll
  for (int nn = 0; nn < 4; ++nn) {
    int c = n0 + wc * 64 + nn * 16 + rlane;
    float bv = bias[c];
#pragma unroll
    for (int m = 0; m < 4; ++m) {
      int rbase = m0 + wr * 64 + m * 16 + ((lane >> 4) << 2);
#pragma unroll
      for (int q = 0; q < 4; ++q) {
        int r = rbase + q;
        float v = acc[m][nn][q] + bv;
        v = v > 0.f ? v : 0.f;
        Hc[(size_t)(((r >> 7) * 8 + (c >> 6)) * 8192) + (r & 127) * 64 +
           ((c & 63) ^ ((r & 7) << 3))] = f2bf(v);
      }
    }
  }
}

// GEMM2: new_t = relu(h @ w1b + b1b), both operands DMA from pre-swizzled
// chunks; round-6 measured form: 64x256 tile, dead s/o-tile early-exit.
__launch_bounds__(512, 2)
__global__ void k_gemm2(const short* __restrict__ Ac, const short* __restrict__ Bc,
                        const float* __restrict__ bias, const int* __restrict__ index,
                        const int* __restrict__ rel_lens,
                        float* __restrict__ contrib, float* __restrict__ out) {
  __shared__ short lA[2][64 * 64];
  __shared__ short lB[2][256 * 64];
  const int g = blockIdx.x;
  const int lid = (g & 7) * 768 + (g >> 3);   // 6144 blocks, bijective
  const int rb = lid / 6, cb = lid - rb * 6;
  const int m0 = rb * 64, n0 = cb * 256;
  const int region = n0 >> 9;  // 0: s, 1: p, 2: o
  const int b = m0 >> 11;      // tile is within one batch
  const int rel = rel_lens[b];
  if (region != 1 && (m0 & 2047) >= rel) return;  // dead s/o tile: exact skip

  const int tid = threadIdx.x;
  const int lane = tid & 63, w = tid >> 6;
  const int wr = w >> 2, wc = w & 3;
  const int rlane = lane & 15, ksel = (lane >> 4) * 8;
  const short* achunk = Ac + (size_t)((m0 >> 7) * 8) * 8192 + (m0 & 127) * 64;
  const short* bchunk = Bc + (size_t)(cb * 8) * 16384;

  f32x4 acc[2][4] = {};

  auto issue_stage = [&](int nb, int kt) {
    gload_lds16(achunk + (size_t)kt * 8192 + tid * 8, &lA[nb][tid * 8]);
    const short* src = bchunk + (size_t)kt * 16384 + tid * 8;
#pragma unroll
    for (int i = 0; i < 4; ++i)
      gload_lds16(src + i * 4096, &lB[nb][tid * 8 + i * 4096]);
  };
  auto compute = [&](int cu) {
#pragma unroll
    for (int j = 0; j < 2; ++j) {
      int k0 = j * 32 + ksel;
      s16x8 af[2], bfr[4];
#pragma unroll
      for (int m = 0; m < 2; ++m) {
        int row = wr * 32 + m * 16 + rlane;
        af[m] = *(const s16x8*)&lA[cu][row * 64 + (k0 ^ ((row & 7) << 3))];
      }
#pragma unroll
      for (int n = 0; n < 4; ++n) {
        int row = wc * 64 + n * 16 + rlane;
        bfr[n] = *(const s16x8*)&lB[cu][row * 64 + (k0 ^ ((row & 7) << 3))];
      }
#pragma unroll
      for (int m = 0; m < 2; ++m)
#pragma unroll
        for (int n = 0; n < 4; ++n)
          acc[m][n] = __builtin_amdgcn_mfma_f32_16x16x32_bf16(af[m], bfr[n], acc[m][n], 0, 0, 0);
    }
  };

  issue_stage(0, 0);
  asm volatile("s_waitcnt vmcnt(0)" ::: "memory");
  __syncthreads();
  for (int kt = 0; kt < 8; ++kt) {
    const int cu = kt & 1;
    if (kt < 7) issue_stage(cu ^ 1, kt + 1);
    compute(cu);
    if (kt < 7) {
      asm volatile("s_waitcnt vmcnt(0)" ::: "memory");
      __syncthreads();
    }
  }

  float bv[4]; int cg[4];
#pragma unroll
  for (int n = 0; n < 4; ++n) { cg[n] = n0 + wc * 64 + n * 16 + rlane; bv[n] = bias[cg[n]]; }

  if (region == 1) {
    float* po = out + (size_t)NBATCH * NOBJ * NH;  // p_vecs region of d_out
#pragma unroll
    for (int m = 0; m < 2; ++m) {
      int rbase = m0 + wr * 32 + m * 16 + ((lane >> 4) << 2);
#pragma unroll
      for (int q = 0; q < 4; ++q) {
#pragma unroll
        for (int n = 0; n < 4; ++n) {
          float v = acc[m][n][q] + bv[n];
          v = v > 0.f ? v : 0.f;
          po[(size_t)(rbase + q) * NH + (cg[n] & 511)] = v;
        }
      }
    }
  } else {
    const int sel = region >> 1;          // 0 for s, 1 for o
#pragma unroll
    for (int m = 0; m < 2; ++m) {
      int rbase = m0 + wr * 32 + m * 16 + ((lane >> 4) << 2);
#pragma unroll
      for (int q = 0; q < 4; ++q) {
        int r = rbase + q;
        if ((r & 2047) < rel) {
          int idx = index[2 * r + sel];
          float* dst = contrib + ((b * NOBJ + idx) << 9);
#pragma unroll
          for (int n = 0; n < 4; ++n) {
            float v = acc[m][n][q] + bv[n];
            v = v > 0.f ? v : 0.f;
            atomicAdd(dst + (cg[n] & 511), v);
          }
        }
      }
    }
  }
}

// pooled[b] = cumsum_b(contrib)
__global__ void k_cumsum(const float* __restrict__ contrib, float* __restrict__ pooled) {
  int i = blockIdx.x * 256 + threadIdx.x;
  if (i >= NOBJ * NH) return;
  float a = 0.f;
#pragma unroll
  for (int b = 0; b < NBATCH; ++b) {
    a += contrib[b * (NOBJ * NH) + i];
    pooled[b * (NOBJ * NH) + i] = a;
  }
}

// new_obj = relu(relu(pooled @ w2a + b2a) @ w2b + b2b), one block per (b,o)
// row. 4 independent FMA chains per thread.
__global__ void k_mlp2(const float* __restrict__ pooled,
                       const float* __restrict__ w2a, const float* __restrict__ b2a,
                       const float* __restrict__ w2b, const float* __restrict__ b2b,
                       float* __restrict__ out) {
  __shared__ float pr[NH];
  __shared__ float hr[NH];
  int row = blockIdx.x;
  int tid = threadIdx.x;
  pr[tid]       = pooled[(size_t)row * NH + tid];
  pr[tid + 256] = pooled[(size_t)row * NH + tid + 256];
  __syncthreads();
  {
    float a0 = 0.f, a1 = 0.f, b0 = 0.f, b1 = 0.f;
    for (int k = 0; k < NH; k += 2) {
      float p0 = pr[k], p1 = pr[k + 1];
      a0 += p0 * w2a[(size_t)k * NH + tid];
      b0 += p0 * w2a[(size_t)k * NH + tid + 256];
      a1 += p1 * w2a[(size_t)(k + 1) * NH + tid];
      b1 += p1 * w2a[(size_t)(k + 1) * NH + tid + 256];
    }
    float s0 = a0 + a1 + b2a[tid], s1 = b0 + b1 + b2a[tid + 256];
    hr[tid]       = s0 > 0.f ? s0 : 0.f;
    hr[tid + 256] = s1 > 0.f ? s1 : 0.f;
  }
  __syncthreads();
  {
    float a0 = 0.f, a1 = 0.f, b0 = 0.f, b1 = 0.f;
    for (int k = 0; k < NH; k += 2) {
      float h0 = hr[k], h1 = hr[k + 1];
      a0 += h0 * w2b[(size_t)k * NH + tid];
      b0 += h0 * w2b[(size_t)k * NH + tid + 256];
      a1 += h1 * w2b[(size_t)(k + 1) * NH + tid];
      b1 += h1 * w2b[(size_t)(k + 1) * NH + tid + 256];
    }
    float s0 = a0 + a1 + b2b[tid], s1 = b0 + b1 + b2b[tid + 256];
    out[(size_t)row * NH + tid]       = s0 > 0.f ? s0 : 0.f;
    out[(size_t)row * NH + tid + 256] = s1 > 0.f ? s1 : 0.f;
  }
}

extern "C" void kernel_launch(void* const* d_in, const int* in_sizes, int n_in,
                              void* d_out, int out_size, void* d_ws, size_t ws_size,
                              hipStream_t stream) {
  const float* trip     = (const float*)d_in[0];
  const int*   index    = (const int*)d_in[1];
  const int*   rel_lens = (const int*)d_in[2];
  const float* w1a      = (const float*)d_in[3];
  const float* b1a      = (const float*)d_in[4];
  const float* w1b      = (const float*)d_in[5];
  const float* b1b      = (const float*)d_in[6];
  const float* w2a      = (const float*)d_in[7];
  const float* b2a      = (const float*)d_in[8];
  const float* w2b      = (const float*)d_in[9];
  const float* b2b      = (const float*)d_in[10];
  float* out = (float*)d_out;

  char* ws = (char*)d_ws;
  short* wt1a    = (short*)(ws);                          // 512*1536 bf16  (1.50 MB)
  short* wt1b    = (short*)(ws + 1572864);                // 1536*512 bf16  (1.50 MB)
  short* hbuf    = (short*)(ws + 3145728);                // 65536*512 bf16 (64 MB), chunked
  float* contrib = (float*)(ws + 70254592);               // 32*18*512 f32
  float* pooled  = contrib + NBATCH * NOBJ * NH;

  k_zero<<<1152, 256, 0, stream>>>(contrib, NBATCH * NOBJ * NH);
  k_prep<<<3072, 256, 0, stream>>>(w1a, wt1a, KIN, NH, 24, NH * 1536);
  k_prep<<<3072, 256, 0, stream>>>(w1b, wt1b, NH, NTOT, 8, NTOT * NH);
  k_gemm1<<<1024, 512, 0, stream>>>(trip, wt1a, b1a, hbuf);
  k_gemm2<<<6144, 512, 0, stream>>>(hbuf, wt1b, b1b, index, rel_lens, contrib, out);
  k_cumsum<<<36, 256, 0, stream>>>(contrib, pooled);
  k_mlp2<<<576, 256, 0, stream>>>(pooled, w2a, b2a, w2b, b2b, out);
}